// Round 13
// baseline (440.273 us; speedup 1.0000x reference)
//
#include <hip/hip_runtime.h>
#include <math.h>

constexpr float LEAKY = 0.2f;

__device__ __forceinline__ float4 ldf4(const float* p){ return *reinterpret_cast<const float4*>(p); }
__device__ __forceinline__ void stf4(float* p, float4 v){ *reinterpret_cast<float4*>(p) = v; }
__device__ __forceinline__ float dot4(float4 a, float4 b){ return a.x*b.x + a.y*b.y + a.z*b.z + a.w*b.w; }
__device__ __forceinline__ float4 fma4(float s, float4 b, float4 acc){
    acc.x += s*b.x; acc.y += s*b.y; acc.z += s*b.z; acc.w += s*b.w; return acc;
}
__device__ __forceinline__ float lrelu(float f){ return f > 0.f ? f : LEAKY*f; }
__device__ __forceinline__ float4 lrelu4(float s, float4 t){
    float4 r; r.x = lrelu(s+t.x); r.y = lrelu(s+t.y); r.z = lrelu(s+t.z); r.w = lrelu(s+t.w); return r;
}
__device__ __forceinline__ float vmax4(float4 v){ return fmaxf(fmaxf(v.x,v.y), fmaxf(v.z,v.w)); }
__device__ __forceinline__ float vsum4(float4 v){ return v.x+v.y+v.z+v.w; }
__device__ __forceinline__ float4 exp4(float4 a, float mx){
    float4 r; r.x = __expf(a.x-mx); r.y = __expf(a.y-mx); r.z = __expf(a.z-mx); r.w = __expf(a.w-mx); return r;
}

// ws layout (floats): wv[12*64]@0 | WspT0[12*64]@768 | WspT1[5*64]@1536 | WtpT0[32*64]@1856 | WtpT1[16*64]@3904
__global__ void prep_kernel(const float* __restrict__ W,
    const float* a0, const float* a1, const float* a2,  const float* a3,
    const float* a4, const float* a5, const float* a6,  const float* a7,
    const float* a8, const float* a9, const float* a10, const float* a11,
    const float* __restrict__ Wsp0, const float* __restrict__ Wsp1,
    const float* __restrict__ Wtp0, const float* __restrict__ Wtp1,
    float* __restrict__ ws)
{
    int blk = blockIdx.x, t = threadIdx.x;
    if (blk < 12) {
        const float* as[12] = {a0,a1,a2,a3,a4,a5,a6,a7,a8,a9,a10,a11};
        const float* a = as[blk];
        float s = 0.f;
        #pragma unroll
        for (int h = 0; h < 128; ++h) s += W[t*128 + h] * a[h];
        ws[blk*64 + t] = s;
    } else if (blk == 12) {
        for (int i = t; i < 768; i += 64) { int k = i >> 6, c = i & 63; ws[768 + i] = Wsp0[c*12 + k]; }
    } else if (blk == 13) {
        for (int i = t; i < 320; i += 64) { int k = i >> 6, c = i & 63; ws[1536 + i] = Wsp1[c*5 + k]; }
    } else if (blk == 14) {
        for (int i = t; i < 2048; i += 64) { int k = i >> 6, c = i & 63; ws[1856 + i] = Wtp0[c*32 + k]; }
    } else {
        for (int i = t; i < 1024; i += 64) { int k = i >> 6, c = i & 63; ws[3904 + i] = Wtp1[c*16 + k]; }
    }
}

// ================== TEMPORAL: 6400 graphs of 64 nodes, 512 threads ==================
// R12 fixed: S0T is [32 rows][64 cols] -> row stride 68 (was 60: rows aliased).
// xr grown to 4608 floats; oS0T=2432, 2432+32*68=4608.
__global__ __launch_bounds__(512, 4)
void temporal_kernel(const float* __restrict__ src, const float* __restrict__ wvec_g,
                     const float* __restrict__ Wp0, const float* __restrict__ b0,
                     const float* __restrict__ Wp1, const float* __restrict__ b1,
                     float* __restrict__ out, int nwg8)
{
    constexpr int NT = 512;
    constexpr int oA1 = 0;          // [32][36]  A1 -> B (in place)
    constexpr int oP1 = 1152;       // [32][20]  P1 -> T1
    constexpr int oS1 = 1792;       // [32][20]
    constexpr int oS0T = 2432;      // [32][68]  S0T (x0 dead after PH1)

    __shared__ __align__(16) float xr[4608];   // x0[64][68]; tenants oA1/oP1/oS1/oS0T
    __shared__ __align__(16) float A0[4352];   // attn0 -> fusion (in place) [64][68]
    __shared__ __align__(16) float PR[2304];   // P0[64][36] -> M1[64][36]
    __shared__ __align__(16) float S0[2304];   // [64][36]
    __shared__ __align__(16) float P01[1280];  // x0@Wp1 [64][20]
    __shared__ __align__(16) float dv[256];    // 4 x [64] dots of x0 with ws1,wd1,ws2,wd2
    __shared__ __align__(16) float sv[64], tv[64], rx[64], rs[64];
    __shared__ __align__(16) float ua[32], va[32];
    __shared__ __align__(16) float wv[384];

    const int tid = threadIdx.x;
    const int g = (blockIdx.x & 7) * nwg8 + (blockIdx.x >> 3);
    const int b = g / 25, inner = g - b*25;

    for (int i = tid; i < 384; i += NT) wv[i] = wvec_g[i];
    for (int i = tid; i < 4096; i += NT) {
        int c = i >> 6, r = i & 63;
        xr[r*68 + c] = src[((size_t)(b*64 + c)*64 + r)*25 + inner];
    }
    __syncthreads();

    // ---- PH1: {all 6 dots per x0 row (1 wave) | P0 = x0@Wp0 | P01 = x0@Wp1} ----
    if (tid < 64) {
        float acc[6] = {};
        #pragma unroll
        for (int c4 = 0; c4 < 16; ++c4) {
            float4 xv = ldf4(&xr[tid*68 + 4*c4]);
            #pragma unroll
            for (int d = 0; d < 6; ++d) acc[d] += dot4(xv, ldf4(&wv[d*64 + 4*c4]));
        }
        sv[tid] = acc[0]; tv[tid] = acc[1];
        dv[tid] = acc[2]; dv[64+tid] = acc[3]; dv[128+tid] = acc[4]; dv[192+tid] = acc[5];
    }
    for (int i = tid; i < 512; i += NT) {
        int p = i >> 3, k4 = i & 7;
        float4 acc = {0,0,0,0};
        #pragma unroll
        for (int c4 = 0; c4 < 16; ++c4) {
            float4 xv = ldf4(&xr[p*68 + 4*c4]);
            acc = fma4(xv.x, ldf4(&Wp0[(4*c4+0)*32 + 4*k4]), acc);
            acc = fma4(xv.y, ldf4(&Wp0[(4*c4+1)*32 + 4*k4]), acc);
            acc = fma4(xv.z, ldf4(&Wp0[(4*c4+2)*32 + 4*k4]), acc);
            acc = fma4(xv.w, ldf4(&Wp0[(4*c4+3)*32 + 4*k4]), acc);
        }
        stf4(&PR[p*36 + 4*k4], acc);
    }
    for (int i = tid; i < 256; i += NT) {
        int p = i >> 2, k4 = i & 3;
        float4 acc = {0,0,0,0};
        #pragma unroll
        for (int c4 = 0; c4 < 16; ++c4) {
            float4 xv = ldf4(&xr[p*68 + 4*c4]);
            acc = fma4(xv.x, ldf4(&Wp1[(4*c4+0)*16 + 4*k4]), acc);
            acc = fma4(xv.y, ldf4(&Wp1[(4*c4+1)*16 + 4*k4]), acc);
            acc = fma4(xv.z, ldf4(&Wp1[(4*c4+2)*16 + 4*k4]), acc);
            acc = fma4(xv.w, ldf4(&Wp1[(4*c4+3)*16 + 4*k4]), acc);
        }
        stf4(&P01[p*20 + 4*k4], acc);
    }
    __syncthreads();

    // ---- PH2: A0 = lrelu(s + t^T) ----
    for (int i = tid; i < 1024; i += NT) {
        int p = i >> 4, q4 = i & 15;
        stf4(&A0[p*68 + 4*q4], lrelu4(sv[p], ldf4(&tv[4*q4])));
    }
    __syncthreads();

    // ---- PH3: S0raw = A0 @ P0 + b0 (2p x 8k tiles, 128 thr, b128 A0 reads) ----
    if (tid < 128) {
        int p0 = tid >> 2, k8 = tid & 3;
        float4 a00 = ldf4(&b0[8*k8]), a01 = ldf4(&b0[8*k8 + 4]);
        float4 a10 = a00, a11 = a01;
        #pragma unroll
        for (int m4 = 0; m4 < 16; ++m4) {
            float4 av0 = ldf4(&A0[p0*68 + 4*m4]);
            float4 av1 = ldf4(&A0[(p0+32)*68 + 4*m4]);
            const float* f0 = (const float*)&av0;
            const float* f1 = (const float*)&av1;
            #pragma unroll
            for (int j = 0; j < 4; ++j) {
                float4 pr0 = ldf4(&PR[(4*m4+j)*36 + 8*k8]);
                float4 pr1 = ldf4(&PR[(4*m4+j)*36 + 8*k8 + 4]);
                a00 = fma4(f0[j], pr0, a00); a01 = fma4(f0[j], pr1, a01);
                a10 = fma4(f1[j], pr0, a10); a11 = fma4(f1[j], pr1, a11);
            }
        }
        stf4(&S0[p0*36 + 8*k8], a00);      stf4(&S0[p0*36 + 8*k8 + 4], a01);
        stf4(&S0[(p0+32)*36 + 8*k8], a10); stf4(&S0[(p0+32)*36 + 8*k8 + 4], a11);
    }
    __syncthreads();

    // ---- PH4: row softmax S0 (8 lanes/row); also write S0T [32][68] ----
    {
        int p = tid >> 3, l = tid & 7;
        float4 v = ldf4(&S0[p*36 + 4*l]);
        float mx = vmax4(v);
        mx = fmaxf(mx, __shfl_xor(mx,1)); mx = fmaxf(mx, __shfl_xor(mx,2)); mx = fmaxf(mx, __shfl_xor(mx,4));
        v = exp4(v, mx);
        float sm = vsum4(v);
        sm += __shfl_xor(sm,1); sm += __shfl_xor(sm,2); sm += __shfl_xor(sm,4);
        float inv = 1.f/sm;
        v.x *= inv; v.y *= inv; v.z *= inv; v.w *= inv;
        stf4(&S0[p*36 + 4*l], v);
        xr[oS0T + (4*l+0)*68 + p] = v.x;
        xr[oS0T + (4*l+1)*68 + p] = v.y;
        xr[oS0T + (4*l+2)*68 + p] = v.z;
        xr[oS0T + (4*l+3)*68 + p] = v.w;
    }
    __syncthreads();

    // ---- PH5: {P1 = S0^T@P01 via S0T (64 thr, 2 rows) | s1/t1/u/v row-dots (thr 64..191)} ----
    if (tid < 64) {
        int k0 = tid >> 2, j4 = tid & 3;   // rows k0, k0+16; cols 4*j4
        float4 acc0 = {0,0,0,0}, acc1 = {0,0,0,0};
        #pragma unroll
        for (int p4 = 0; p4 < 16; ++p4) {
            float4 s0 = ldf4(&xr[oS0T + k0*68 + 4*p4]);
            float4 s1 = ldf4(&xr[oS0T + (k0+16)*68 + 4*p4]);
            const float* f0 = (const float*)&s0;
            const float* f1 = (const float*)&s1;
            #pragma unroll
            for (int j = 0; j < 4; ++j) {
                float4 pv = ldf4(&P01[(4*p4+j)*20 + 4*j4]);
                acc0 = fma4(f0[j], pv, acc0);
                acc1 = fma4(f1[j], pv, acc1);
            }
        }
        stf4(&xr[oP1 + k0*20 + 4*j4], acc0);
        stf4(&xr[oP1 + (k0+16)*20 + 4*j4], acc1);
    } else if (tid < 192) {
        int i = tid - 64;
        int j = i >> 5, k = i & 31;
        const float* d = dv + j*64;
        float acc = 0.f;
        #pragma unroll
        for (int p4 = 0; p4 < 16; ++p4)
            acc += dot4(ldf4(&xr[oS0T + k*68 + 4*p4]), ldf4(&d[4*p4]));
        if (j == 0) sv[k] = acc; else if (j == 1) tv[k] = acc;
        else if (j == 2) ua[k] = acc; else va[k] = acc;
    }
    __syncthreads();

    // ---- PH7: A1 = lrelu(s1 + t1^T) ----
    for (int i = tid; i < 1024; i += NT) {
        int p = i >> 5, q = i & 31;
        xr[oA1 + p*36 + q] = lrelu(sv[p] + tv[q]);
    }
    __syncthreads();

    // ---- PH8: S1raw = A1@P1 + b1 ----
    for (int i = tid; i < 128; i += NT) {
        int p = i >> 2, k4 = i & 3;
        float4 acc = ldf4(&b1[4*k4]);
        #pragma unroll
        for (int m = 0; m < 32; ++m) acc = fma4(xr[oA1 + p*36 + m], ldf4(&xr[oP1 + m*20 + 4*k4]), acc);
        stf4(&xr[oS1 + p*20 + 4*k4], acc);
    }
    __syncthreads();

    // ---- PH9: row softmax S1 (128 thr, 4 lanes/row) ----
    if (tid < 128) {
        int m = tid >> 2, l = tid & 3;
        float4 v = ldf4(&xr[oS1 + m*20 + 4*l]);
        float mx = vmax4(v);
        mx = fmaxf(mx, __shfl_xor(mx,1)); mx = fmaxf(mx, __shfl_xor(mx,2));
        v = exp4(v, mx);
        float sm = vsum4(v);
        sm += __shfl_xor(sm,1); sm += __shfl_xor(sm,2);
        float inv = 1.f/sm;
        v.x *= inv; v.y *= inv; v.z *= inv; v.w *= inv;
        stf4(&xr[oS1 + m*20 + 4*l], v);
    }
    __syncthreads();

    // ---- PH10: rx/rs = S1^T . (u,v) ----
    for (int k = tid; k < 16; k += NT) {
        float a = 0.f, c2 = 0.f;
        #pragma unroll
        for (int n = 0; n < 32; ++n) { float s1 = xr[oS1 + n*20 + k]; a += s1*ua[n]; c2 += s1*va[n]; }
        rx[k] = a; rs[k] = c2;
    }
    __syncthreads();

    // ---- PH11: T1 = S1 @ A2 (A2 = lrelu(rx + rs^T) on the fly), into oP1 ----
    {
        int m = tid >> 4, k = tid & 15;
        float rsk = rs[k];
        float acc = 0.f;
        #pragma unroll
        for (int j = 0; j < 16; ++j)
            acc += xr[oS1 + m*20 + j] * lrelu(rx[j] + rsk);
        xr[oP1 + m*20 + k] = acc;
    }
    __syncthreads();

    // ---- PH11b: B = A1 + T1@S1^T, in place over A1 ----
    for (int i = tid; i < 1024; i += NT) {
        int m = i >> 5, n = i & 31;
        float acc = xr[oA1 + m*36 + n];
        #pragma unroll
        for (int j4 = 0; j4 < 4; ++j4)
            acc += dot4(ldf4(&xr[oP1 + m*20 + 4*j4]), ldf4(&xr[oS1 + n*20 + 4*j4]));
        xr[oA1 + m*36 + n] = acc;
    }
    __syncthreads();

    // ---- PH11c: M1 = S0 @ B (2p x 8k tiles, 128 thr, b128 S0-row reads) ----
    if (tid < 128) {
        int p0 = tid >> 2, k8 = tid & 3;
        float4 a00 = {0,0,0,0}, a01 = {0,0,0,0}, a10 = {0,0,0,0}, a11 = {0,0,0,0};
        #pragma unroll
        for (int m4 = 0; m4 < 8; ++m4) {
            float4 av0 = ldf4(&S0[p0*36 + 4*m4]);
            float4 av1 = ldf4(&S0[(p0+32)*36 + 4*m4]);
            const float* f0 = (const float*)&av0;
            const float* f1 = (const float*)&av1;
            #pragma unroll
            for (int j = 0; j < 4; ++j) {
                float4 b0v = ldf4(&xr[oA1 + (4*m4+j)*36 + 8*k8]);
                float4 b1v = ldf4(&xr[oA1 + (4*m4+j)*36 + 8*k8 + 4]);
                a00 = fma4(f0[j], b0v, a00); a01 = fma4(f0[j], b1v, a01);
                a10 = fma4(f1[j], b0v, a10); a11 = fma4(f1[j], b1v, a11);
            }
        }
        stf4(&PR[p0*36 + 8*k8], a00);      stf4(&PR[p0*36 + 8*k8 + 4], a01);
        stf4(&PR[(p0+32)*36 + 8*k8], a10); stf4(&PR[(p0+32)*36 + 8*k8 + 4], a11);
    }
    __syncthreads();

    // ---- PH12: fusion += M1@S0^T via S0T (2p x 8q tiles, 256 thr, all-b128) ----
    if (tid < 256) {
        int p0 = tid >> 3, q8 = tid & 7;
        float4 a00 = ldf4(&A0[p0*68 + 8*q8]);
        float4 a01 = ldf4(&A0[p0*68 + 8*q8 + 4]);
        float4 a10 = ldf4(&A0[(p0+32)*68 + 8*q8]);
        float4 a11 = ldf4(&A0[(p0+32)*68 + 8*q8 + 4]);
        #pragma unroll
        for (int m4 = 0; m4 < 8; ++m4) {
            float4 av0 = ldf4(&PR[p0*36 + 4*m4]);
            float4 av1 = ldf4(&PR[(p0+32)*36 + 4*m4]);
            const float* f0 = (const float*)&av0;
            const float* f1 = (const float*)&av1;
            #pragma unroll
            for (int j = 0; j < 4; ++j) {
                float4 s0v = ldf4(&xr[oS0T + (4*m4+j)*68 + 8*q8]);
                float4 s1v = ldf4(&xr[oS0T + (4*m4+j)*68 + 8*q8 + 4]);
                a00 = fma4(f0[j], s0v, a00); a01 = fma4(f0[j], s1v, a01);
                a10 = fma4(f1[j], s0v, a10); a11 = fma4(f1[j], s1v, a11);
            }
        }
        stf4(&A0[p0*68 + 8*q8], a00);      stf4(&A0[p0*68 + 8*q8 + 4], a01);
        stf4(&A0[(p0+32)*68 + 8*q8], a10); stf4(&A0[(p0+32)*68 + 8*q8 + 4], a11);
    }
    __syncthreads();

    // ---- epilogue: row softmax of fusion + write (8 lanes/row, 512 thr) ----
    {
        int p = tid >> 3, l = tid & 7;
        float4 v1 = ldf4(&A0[p*68 + 4*l]);
        float4 v2 = ldf4(&A0[p*68 + 32 + 4*l]);
        float mx = fmaxf(vmax4(v1), vmax4(v2));
        mx = fmaxf(mx, __shfl_xor(mx,1)); mx = fmaxf(mx, __shfl_xor(mx,2)); mx = fmaxf(mx, __shfl_xor(mx,4));
        float4 e1 = exp4(v1, mx), e2 = exp4(v2, mx);
        float sm = vsum4(e1) + vsum4(e2);
        sm += __shfl_xor(sm,1); sm += __shfl_xor(sm,2); sm += __shfl_xor(sm,4);
        float inv = 1.f/sm;
        e1.x*=inv; e1.y*=inv; e1.z*=inv; e1.w*=inv;
        e2.x*=inv; e2.y*=inv; e2.z*=inv; e2.w*=inv;
        size_t base = (size_t)g*4096 + (size_t)p*64;
        stf4(&out[base + 4*l], e1);
        stf4(&out[base + 32 + 4*l], e2);
    }
}

// ================== SPATIAL: 16384 graphs of 25 nodes, 256 threads ==================
__global__ __launch_bounds__(256, 4)
void spatial_kernel(const float* __restrict__ src, const float* __restrict__ wvg,
                    const float* __restrict__ WpT0, const float* __restrict__ WpT1,
                    const float* __restrict__ b0, const float* __restrict__ b1,
                    float* __restrict__ out, int nwg8)
{
    __shared__ __align__(16) float Rx0[1700];
    __shared__ __align__(16) float RA0[700];
    __shared__ __align__(16) float RPR[816];
    __shared__ __align__(16) float RS0[500];
    __shared__ __align__(16) float sv[32], tv[32], ua[32], va[32], rxa[8], rsa[8];

    float* x0  = Rx0;
    float* A1  = Rx0;          // [12][20] -> B (in place)
    float* A1T = Rx0 + 240;    // [12][20] -> BT (in place)
    float* P1T = Rx0 + 480;    // [5][12]
    float* S1  = Rx0 + 540;    // [12][12]
    float* T1  = Rx0 + 744;    // [12][5]
    float* A0  = RA0;
    float* P0T = RPR;
    float* x1  = RPR;
    float* M1  = RPR;
    float* S0  = RS0;

    const int t = threadIdx.x;
    const int g = (blockIdx.x & 7) * nwg8 + (blockIdx.x >> 3);
    const int b = g >> 6, inner = g & 63;
    const float* srcb = src + (size_t)b*102400 + inner*25;

    for (int i = t; i < 400; i += 256) {
        int r = i % 25, c0 = (i / 25) << 2;
        float4 v;
        v.x = srcb[(c0+0)*1600 + r];
        v.y = srcb[(c0+1)*1600 + r];
        v.z = srcb[(c0+2)*1600 + r];
        v.w = srcb[(c0+3)*1600 + r];
        stf4(&x0[r*68 + c0], v);
    }
    __syncthreads();

    if (t < 50) {
        int which = t / 25, p = t - which*25;
        const float* w = wvg + which*64;
        float a = 0.f;
        #pragma unroll
        for (int c4 = 0; c4 < 16; ++c4) a += dot4(ldf4(&x0[p*68 + 4*c4]), ldf4(&w[4*c4]));
        if (which) tv[p] = a; else sv[p] = a;
    }
    for (int i = t; i < 336; i += 256) {
        int k = i / 28, m = i - k*28;
        float a = 0.f;
        if (m < 25) {
            #pragma unroll
            for (int c4 = 0; c4 < 16; ++c4) a += dot4(ldf4(&WpT0[k*64 + 4*c4]), ldf4(&x0[m*68 + 4*c4]));
        }
        P0T[k*28 + m] = a;
    }
    __syncthreads();

    for (int i = t; i < 700; i += 256) {
        int p = i / 28, q = i - p*28;
        A0[i] = (q < 25) ? lrelu(sv[p] + tv[q]) : -1e30f;
    }
    __syncthreads();

    for (int i = t; i < 300; i += 256) {
        int p = i / 12, k = i - p*12;
        float acc = b0[k];
        #pragma unroll
        for (int m4 = 0; m4 < 7; ++m4) acc += dot4(ldf4(&A0[p*28 + 4*m4]), ldf4(&P0T[k*28 + 4*m4]));
        S0[p*20 + k] = acc;
    }
    __syncthreads();

    if (t < 25) {
        float4 r[3]; float mx = -1e30f;
        #pragma unroll
        for (int u = 0; u < 3; ++u) { r[u] = ldf4(&S0[t*20 + 4*u]); mx = fmaxf(mx, vmax4(r[u])); }
        float sm = 0.f;
        #pragma unroll
        for (int u = 0; u < 3; ++u) { r[u] = exp4(r[u], mx); sm += vsum4(r[u]); }
        float inv = 1.f/sm;
        #pragma unroll
        for (int u = 0; u < 3; ++u) {
            r[u].x *= inv; r[u].y *= inv; r[u].z *= inv; r[u].w *= inv;
            stf4(&S0[t*20 + 4*u], r[u]);
        }
    }
    __syncthreads();

    if (t < 96) {
        int k = t >> 3, c0 = (t & 7) << 3;
        float4 a = {0,0,0,0}, bb = {0,0,0,0};
        #pragma unroll
        for (int p = 0; p < 25; ++p) {
            float s = S0[p*20 + k];
            a  = fma4(s, ldf4(&x0[p*68 + c0]), a);
            bb = fma4(s, ldf4(&x0[p*68 + c0 + 4]), bb);
        }
        stf4(&x1[k*68 + c0], a);
        stf4(&x1[k*68 + c0 + 4], bb);
    }
    __syncthreads();

    if (t < 48) {
        int which = t / 12, p = t - which*12;
        const float* w = wvg + (2+which)*64;
        float a = 0.f;
        #pragma unroll
        for (int c4 = 0; c4 < 16; ++c4) a += dot4(ldf4(&x1[p*68 + 4*c4]), ldf4(&w[4*c4]));
        if (which == 0) sv[p] = a; else if (which == 1) tv[p] = a;
        else if (which == 2) ua[p] = a; else va[p] = a;
    }
    for (int i = t; i < 60; i += 256) {
        int j = i / 12, k = i - j*12;
        float a = 0.f;
        #pragma unroll
        for (int c4 = 0; c4 < 16; ++c4) a += dot4(ldf4(&WpT1[j*64 + 4*c4]), ldf4(&x1[k*68 + 4*c4]));
        P1T[j*12 + k] = a;
    }
    __syncthreads();

    // A1, A1T
    for (int i = t; i < 288; i += 256) {
        int mat = i / 144, rr = (i - mat*144) / 12, q = i % 12;
        if (mat == 0) A1 [rr*20 + q] = lrelu(sv[rr] + tv[q]);
        else          A1T[rr*20 + q] = lrelu(sv[q] + tv[rr]);
    }
    __syncthreads();

    // G1: S1raw = A1@P1 + b1
    for (int i = t; i < 60; i += 256) {
        int m = i / 5, j = i - m*5;
        float acc = b1[j];
        #pragma unroll
        for (int k4 = 0; k4 < 3; ++k4) acc += dot4(ldf4(&A1[m*20 + 4*k4]), ldf4(&P1T[j*12 + 4*k4]));
        S1[m*12 + j] = acc;
    }
    __syncthreads();

    // G2: softmax S1 rows
    if (t < 12) {
        float mx = -1e30f;
        float r0 = S1[t*12+0], r1 = S1[t*12+1], r2 = S1[t*12+2], r3 = S1[t*12+3], r4 = S1[t*12+4];
        mx = fmaxf(fmaxf(fmaxf(r0,r1), fmaxf(r2,r3)), r4);
        r0 = __expf(r0-mx); r1 = __expf(r1-mx); r2 = __expf(r2-mx); r3 = __expf(r3-mx); r4 = __expf(r4-mx);
        float inv = 1.f/(r0+r1+r2+r3+r4);
        S1[t*12+0] = r0*inv; S1[t*12+1] = r1*inv; S1[t*12+2] = r2*inv; S1[t*12+3] = r3*inv; S1[t*12+4] = r4*inv;
    }
    __syncthreads();

    // G2b: rxa/rsa = S1^T . (u,v)
    if (t < 10) {
        int which = t / 5, k = t - which*5;
        float a = 0.f;
        #pragma unroll
        for (int n = 0; n < 12; ++n) a += S1[n*12 + k] * (which ? va[n] : ua[n]);
        if (which) rsa[k] = a; else rxa[k] = a;
    }
    __syncthreads();

    // G3: T1 = S1 @ A2 (A2 = lrelu(rxa + rsa^T) on the fly)  [12][5]
    if (t < 60) {
        int m = t / 5, k = t - m*5;
        float rsk = rsa[k];
        float acc = 0.f;
        #pragma unroll
        for (int j = 0; j < 5; ++j) acc += S1[m*12 + j] * lrelu(rxa[j] + rsk);
        T1[m*5 + k] = acc;
    }
    __syncthreads();

    // G4: B = A1 + T1@S1^T (in place); BT into A1T
    if (t < 144) {
        int m = t / 12, n = t - m*12;
        float acc = A1[m*20 + n];
        #pragma unroll
        for (int j = 0; j < 5; ++j) acc += T1[m*5 + j] * S1[n*12 + j];
        A1[m*20 + n] = acc;
        A1T[n*20 + m] = acc;
    }
    __syncthreads();

    // G5: M1 = S0 @ B (row-dot with BT in A1T)
    for (int i = t; i < 300; i += 256) {
        int p = i / 12, k = i - p*12;
        float acc = 0.f;
        #pragma unroll
        for (int m4 = 0; m4 < 3; ++m4) acc += dot4(ldf4(&S0[p*20 + 4*m4]), ldf4(&A1T[k*20 + 4*m4]));
        M1[p*20 + k] = acc;
    }
    __syncthreads();

    // G6: fusion = A0 + M1@S0^T
    for (int i = t; i < 625; i += 256) {
        int p = i / 25, q = i - p*25;
        float acc = A0[p*28 + q];
        #pragma unroll
        for (int m4 = 0; m4 < 3; ++m4) acc += dot4(ldf4(&M1[p*20 + 4*m4]), ldf4(&S0[q*20 + 4*m4]));
        A0[p*28 + q] = acc;
    }
    __syncthreads();

    // stats
    if (t < 25) {
        float4 r[7]; float mx = -1e30f;
        #pragma unroll
        for (int u = 0; u < 7; ++u) { r[u] = ldf4(&A0[t*28 + 4*u]); mx = fmaxf(mx, vmax4(r[u])); }
        float sm = 0.f;
        #pragma unroll
        for (int u = 0; u < 7; ++u) sm += vsum4(exp4(r[u], mx));
        sv[t] = mx; tv[t] = 1.f/sm;
    }
    __syncthreads();

    for (int i = t; i < 625; i += 256) {
        int p = i / 25, q = i - p*25;
        out[(size_t)g*625 + i] = __expf(A0[p*28 + q] - sv[p]) * tv[p];
    }
}

extern "C" void kernel_launch(void* const* d_in, const int* in_sizes, int n_in,
                              void* d_out, int out_size, void* d_ws, size_t ws_size,
                              hipStream_t stream) {
    const float* src = (const float*)d_in[0];
    const float* W   = (const float*)d_in[1];
    float* ws = (float*)d_ws;

    prep_kernel<<<16, 64, 0, stream>>>(W,
        (const float*)d_in[2],  (const float*)d_in[3],
        (const float*)d_in[6],  (const float*)d_in[7],
        (const float*)d_in[10], (const float*)d_in[11],
        (const float*)d_in[4],  (const float*)d_in[5],
        (const float*)d_in[8],  (const float*)d_in[9],
        (const float*)d_in[12], (const float*)d_in[13],
        (const float*)d_in[14], (const float*)d_in[16],
        (const float*)d_in[18], (const float*)d_in[20],
        ws);

    float* out = (float*)d_out;
    spatial_kernel<<<16384, 256, 0, stream>>>(
        src, ws, ws + 768, ws + 1536,
        (const float*)d_in[15], (const float*)d_in[17],
        out, 16384/8);
    temporal_kernel<<<6400, 512, 0, stream>>>(
        src, ws + 384,
        (const float*)d_in[18], (const float*)d_in[19],
        (const float*)d_in[20], (const float*)d_in[21],
        out + 10240000, 6400/8);
}

// Round 14
// 436.879 us; speedup vs baseline: 1.0078x; 1.0078x over previous
//
#include <hip/hip_runtime.h>
#include <math.h>

constexpr float LEAKY = 0.2f;

__device__ __forceinline__ float4 ldf4(const float* p){ return *reinterpret_cast<const float4*>(p); }
__device__ __forceinline__ void stf4(float* p, float4 v){ *reinterpret_cast<float4*>(p) = v; }
__device__ __forceinline__ float dot4(float4 a, float4 b){ return a.x*b.x + a.y*b.y + a.z*b.z + a.w*b.w; }
__device__ __forceinline__ float4 fma4(float s, float4 b, float4 acc){
    acc.x += s*b.x; acc.y += s*b.y; acc.z += s*b.z; acc.w += s*b.w; return acc;
}
__device__ __forceinline__ float lrelu(float f){ return f > 0.f ? f : LEAKY*f; }
__device__ __forceinline__ float4 lrelu4(float s, float4 t){
    float4 r; r.x = lrelu(s+t.x); r.y = lrelu(s+t.y); r.z = lrelu(s+t.z); r.w = lrelu(s+t.w); return r;
}
__device__ __forceinline__ float vmax4(float4 v){ return fmaxf(fmaxf(v.x,v.y), fmaxf(v.z,v.w)); }
__device__ __forceinline__ float vsum4(float4 v){ return v.x+v.y+v.z+v.w; }
__device__ __forceinline__ float4 exp4(float4 a, float mx){
    float4 r; r.x = __expf(a.x-mx); r.y = __expf(a.y-mx); r.z = __expf(a.z-mx); r.w = __expf(a.w-mx); return r;
}

// ws layout (floats): wv[12*64]@0 | WspT0[12*64]@768 | WspT1[5*64]@1536 | WtpT0[32*64]@1856 | WtpT1[16*64]@3904
__global__ void prep_kernel(const float* __restrict__ W,
    const float* a0, const float* a1, const float* a2,  const float* a3,
    const float* a4, const float* a5, const float* a6,  const float* a7,
    const float* a8, const float* a9, const float* a10, const float* a11,
    const float* __restrict__ Wsp0, const float* __restrict__ Wsp1,
    const float* __restrict__ Wtp0, const float* __restrict__ Wtp1,
    float* __restrict__ ws)
{
    int blk = blockIdx.x, t = threadIdx.x;
    if (blk < 12) {
        const float* as[12] = {a0,a1,a2,a3,a4,a5,a6,a7,a8,a9,a10,a11};
        const float* a = as[blk];
        float s = 0.f;
        #pragma unroll
        for (int h = 0; h < 128; ++h) s += W[t*128 + h] * a[h];
        ws[blk*64 + t] = s;
    } else if (blk == 12) {
        for (int i = t; i < 768; i += 64) { int k = i >> 6, c = i & 63; ws[768 + i] = Wsp0[c*12 + k]; }
    } else if (blk == 13) {
        for (int i = t; i < 320; i += 64) { int k = i >> 6, c = i & 63; ws[1536 + i] = Wsp1[c*5 + k]; }
    } else if (blk == 14) {
        for (int i = t; i < 2048; i += 64) { int k = i >> 6, c = i & 63; ws[1856 + i] = Wtp0[c*32 + k]; }
    } else {
        for (int i = t; i < 1024; i += 64) { int k = i >> 6, c = i & 63; ws[3904 + i] = Wtp1[c*16 + k]; }
    }
}

// ================== TEMPORAL: 6400 graphs of 64 nodes, 512 threads ==================
// R14: A0 virtualized (rank-1 lrelu(sv+tv^T) recomputed in PH3/PH12); fused
// in-register softmax epilogue. LDS 44.6 KB -> 3 blocks/CU at VGPR 64.
__global__ __launch_bounds__(512, 4)
void temporal_kernel(const float* __restrict__ src, const float* __restrict__ wvec_g,
                     const float* __restrict__ Wp0, const float* __restrict__ b0,
                     const float* __restrict__ Wp1, const float* __restrict__ b1,
                     float* __restrict__ out, int nwg8)
{
    constexpr int NT = 512;
    constexpr int oA1 = 0;          // [32][36]  A1 -> B (in place)
    constexpr int oP1 = 1152;       // [32][20]  P1 -> T1
    constexpr int oS1 = 1792;       // [32][20]
    constexpr int oS0T = 2432;      // [32][68]  S0T (x0 dead after PH1)

    __shared__ __align__(16) float xr[4608];   // x0[64][68]; tenants oA1/oP1/oS1/oS0T
    __shared__ __align__(16) float PR[2304];   // P0[64][36] -> M1[64][36]
    __shared__ __align__(16) float S0[2304];   // [64][36]
    __shared__ __align__(16) float P01[1280];  // x0@Wp1 [64][20]
    __shared__ __align__(16) float dv[256];    // 4 x [64] dots of x0 with ws1,wd1,ws2,wd2
    __shared__ __align__(16) float sv[64], tv[64];         // s0/t0 — live until PH12
    __shared__ __align__(16) float s1v[32], t1v[32], ua[32], va[32];
    __shared__ __align__(16) float rx[16], rs[16];
    __shared__ __align__(16) float wv[384];

    const int tid = threadIdx.x;
    const int g = (blockIdx.x & 7) * nwg8 + (blockIdx.x >> 3);
    const int b = g / 25, inner = g - b*25;

    for (int i = tid; i < 384; i += NT) wv[i] = wvec_g[i];
    for (int i = tid; i < 4096; i += NT) {
        int c = i >> 6, r = i & 63;
        xr[r*68 + c] = src[((size_t)(b*64 + c)*64 + r)*25 + inner];
    }
    __syncthreads();

    // ---- PH1: {all 6 dots per x0 row (1 wave) | P0 = x0@Wp0 | P01 = x0@Wp1} ----
    if (tid < 64) {
        float acc[6] = {};
        #pragma unroll
        for (int c4 = 0; c4 < 16; ++c4) {
            float4 xv = ldf4(&xr[tid*68 + 4*c4]);
            #pragma unroll
            for (int d = 0; d < 6; ++d) acc[d] += dot4(xv, ldf4(&wv[d*64 + 4*c4]));
        }
        sv[tid] = acc[0]; tv[tid] = acc[1];
        dv[tid] = acc[2]; dv[64+tid] = acc[3]; dv[128+tid] = acc[4]; dv[192+tid] = acc[5];
    }
    for (int i = tid; i < 512; i += NT) {
        int p = i >> 3, k4 = i & 7;
        float4 acc = {0,0,0,0};
        #pragma unroll
        for (int c4 = 0; c4 < 16; ++c4) {
            float4 xv = ldf4(&xr[p*68 + 4*c4]);
            acc = fma4(xv.x, ldf4(&Wp0[(4*c4+0)*32 + 4*k4]), acc);
            acc = fma4(xv.y, ldf4(&Wp0[(4*c4+1)*32 + 4*k4]), acc);
            acc = fma4(xv.z, ldf4(&Wp0[(4*c4+2)*32 + 4*k4]), acc);
            acc = fma4(xv.w, ldf4(&Wp0[(4*c4+3)*32 + 4*k4]), acc);
        }
        stf4(&PR[p*36 + 4*k4], acc);
    }
    for (int i = tid; i < 256; i += NT) {
        int p = i >> 2, k4 = i & 3;
        float4 acc = {0,0,0,0};
        #pragma unroll
        for (int c4 = 0; c4 < 16; ++c4) {
            float4 xv = ldf4(&xr[p*68 + 4*c4]);
            acc = fma4(xv.x, ldf4(&Wp1[(4*c4+0)*16 + 4*k4]), acc);
            acc = fma4(xv.y, ldf4(&Wp1[(4*c4+1)*16 + 4*k4]), acc);
            acc = fma4(xv.z, ldf4(&Wp1[(4*c4+2)*16 + 4*k4]), acc);
            acc = fma4(xv.w, ldf4(&Wp1[(4*c4+3)*16 + 4*k4]), acc);
        }
        stf4(&P01[p*20 + 4*k4], acc);
    }
    __syncthreads();

    // ---- PH3: S0raw = A0 @ P0 + b0 with A0 = lrelu(sv+tv^T) on the fly ----
    if (tid < 128) {
        int p0 = tid >> 2, k8 = tid & 3;
        float sp0 = sv[p0], sp1 = sv[p0+32];
        float4 a00 = ldf4(&b0[8*k8]), a01 = ldf4(&b0[8*k8 + 4]);
        float4 a10 = a00, a11 = a01;
        #pragma unroll
        for (int m4 = 0; m4 < 16; ++m4) {
            float4 tv4 = ldf4(&tv[4*m4]);
            float4 f0v = lrelu4(sp0, tv4);
            float4 f1v = lrelu4(sp1, tv4);
            const float* f0 = (const float*)&f0v;
            const float* f1 = (const float*)&f1v;
            #pragma unroll
            for (int j = 0; j < 4; ++j) {
                float4 pr0 = ldf4(&PR[(4*m4+j)*36 + 8*k8]);
                float4 pr1 = ldf4(&PR[(4*m4+j)*36 + 8*k8 + 4]);
                a00 = fma4(f0[j], pr0, a00); a01 = fma4(f0[j], pr1, a01);
                a10 = fma4(f1[j], pr0, a10); a11 = fma4(f1[j], pr1, a11);
            }
        }
        stf4(&S0[p0*36 + 8*k8], a00);      stf4(&S0[p0*36 + 8*k8 + 4], a01);
        stf4(&S0[(p0+32)*36 + 8*k8], a10); stf4(&S0[(p0+32)*36 + 8*k8 + 4], a11);
    }
    __syncthreads();

    // ---- PH4: row softmax S0 (8 lanes/row); also write S0T [32][68] ----
    {
        int p = tid >> 3, l = tid & 7;
        float4 v = ldf4(&S0[p*36 + 4*l]);
        float mx = vmax4(v);
        mx = fmaxf(mx, __shfl_xor(mx,1)); mx = fmaxf(mx, __shfl_xor(mx,2)); mx = fmaxf(mx, __shfl_xor(mx,4));
        v = exp4(v, mx);
        float sm = vsum4(v);
        sm += __shfl_xor(sm,1); sm += __shfl_xor(sm,2); sm += __shfl_xor(sm,4);
        float inv = 1.f/sm;
        v.x *= inv; v.y *= inv; v.z *= inv; v.w *= inv;
        stf4(&S0[p*36 + 4*l], v);
        xr[oS0T + (4*l+0)*68 + p] = v.x;
        xr[oS0T + (4*l+1)*68 + p] = v.y;
        xr[oS0T + (4*l+2)*68 + p] = v.z;
        xr[oS0T + (4*l+3)*68 + p] = v.w;
    }
    __syncthreads();

    // ---- PH5: {P1 = S0^T@P01 via S0T (64 thr, 2 rows) | s1/t1/u/v row-dots (thr 64..191)} ----
    if (tid < 64) {
        int k0 = tid >> 2, j4 = tid & 3;   // rows k0, k0+16; cols 4*j4
        float4 acc0 = {0,0,0,0}, acc1 = {0,0,0,0};
        #pragma unroll
        for (int p4 = 0; p4 < 16; ++p4) {
            float4 s0 = ldf4(&xr[oS0T + k0*68 + 4*p4]);
            float4 s1 = ldf4(&xr[oS0T + (k0+16)*68 + 4*p4]);
            const float* f0 = (const float*)&s0;
            const float* f1 = (const float*)&s1;
            #pragma unroll
            for (int j = 0; j < 4; ++j) {
                float4 pv = ldf4(&P01[(4*p4+j)*20 + 4*j4]);
                acc0 = fma4(f0[j], pv, acc0);
                acc1 = fma4(f1[j], pv, acc1);
            }
        }
        stf4(&xr[oP1 + k0*20 + 4*j4], acc0);
        stf4(&xr[oP1 + (k0+16)*20 + 4*j4], acc1);
    } else if (tid < 192) {
        int i = tid - 64;
        int j = i >> 5, k = i & 31;
        const float* d = dv + j*64;
        float acc = 0.f;
        #pragma unroll
        for (int p4 = 0; p4 < 16; ++p4)
            acc += dot4(ldf4(&xr[oS0T + k*68 + 4*p4]), ldf4(&d[4*p4]));
        if (j == 0) s1v[k] = acc; else if (j == 1) t1v[k] = acc;
        else if (j == 2) ua[k] = acc; else va[k] = acc;
    }
    __syncthreads();

    // ---- PH7: A1 = lrelu(s1 + t1^T) ----
    for (int i = tid; i < 1024; i += NT) {
        int p = i >> 5, q = i & 31;
        xr[oA1 + p*36 + q] = lrelu(s1v[p] + t1v[q]);
    }
    __syncthreads();

    // ---- PH8: S1raw = A1@P1 + b1 ----
    for (int i = tid; i < 128; i += NT) {
        int p = i >> 2, k4 = i & 3;
        float4 acc = ldf4(&b1[4*k4]);
        #pragma unroll
        for (int m = 0; m < 32; ++m) acc = fma4(xr[oA1 + p*36 + m], ldf4(&xr[oP1 + m*20 + 4*k4]), acc);
        stf4(&xr[oS1 + p*20 + 4*k4], acc);
    }
    __syncthreads();

    // ---- PH9: row softmax S1 (128 thr, 4 lanes/row) ----
    if (tid < 128) {
        int m = tid >> 2, l = tid & 3;
        float4 v = ldf4(&xr[oS1 + m*20 + 4*l]);
        float mx = vmax4(v);
        mx = fmaxf(mx, __shfl_xor(mx,1)); mx = fmaxf(mx, __shfl_xor(mx,2));
        v = exp4(v, mx);
        float sm = vsum4(v);
        sm += __shfl_xor(sm,1); sm += __shfl_xor(sm,2);
        float inv = 1.f/sm;
        v.x *= inv; v.y *= inv; v.z *= inv; v.w *= inv;
        stf4(&xr[oS1 + m*20 + 4*l], v);
    }
    __syncthreads();

    // ---- PH10: rx/rs = S1^T . (u,v) ----
    for (int k = tid; k < 16; k += NT) {
        float a = 0.f, c2 = 0.f;
        #pragma unroll
        for (int n = 0; n < 32; ++n) { float s1 = xr[oS1 + n*20 + k]; a += s1*ua[n]; c2 += s1*va[n]; }
        rx[k] = a; rs[k] = c2;
    }
    __syncthreads();

    // ---- PH11: T1 = S1 @ A2 (A2 = lrelu(rx + rs^T) on the fly), into oP1 ----
    {
        int m = tid >> 4, k = tid & 15;
        float rsk = rs[k];
        float acc = 0.f;
        #pragma unroll
        for (int j = 0; j < 16; ++j)
            acc += xr[oS1 + m*20 + j] * lrelu(rx[j] + rsk);
        xr[oP1 + m*20 + k] = acc;
    }
    __syncthreads();

    // ---- PH11b: B = A1 + T1@S1^T, in place over A1 ----
    for (int i = tid; i < 1024; i += NT) {
        int m = i >> 5, n = i & 31;
        float acc = xr[oA1 + m*36 + n];
        #pragma unroll
        for (int j4 = 0; j4 < 4; ++j4)
            acc += dot4(ldf4(&xr[oP1 + m*20 + 4*j4]), ldf4(&xr[oS1 + n*20 + 4*j4]));
        xr[oA1 + m*36 + n] = acc;
    }
    __syncthreads();

    // ---- PH11c: M1 = S0 @ B (2p x 8k tiles, 128 thr, b128 S0-row reads) ----
    if (tid < 128) {
        int p0 = tid >> 2, k8 = tid & 3;
        float4 a00 = {0,0,0,0}, a01 = {0,0,0,0}, a10 = {0,0,0,0}, a11 = {0,0,0,0};
        #pragma unroll
        for (int m4 = 0; m4 < 8; ++m4) {
            float4 av0 = ldf4(&S0[p0*36 + 4*m4]);
            float4 av1 = ldf4(&S0[(p0+32)*36 + 4*m4]);
            const float* f0 = (const float*)&av0;
            const float* f1 = (const float*)&av1;
            #pragma unroll
            for (int j = 0; j < 4; ++j) {
                float4 b0v = ldf4(&xr[oA1 + (4*m4+j)*36 + 8*k8]);
                float4 b1v = ldf4(&xr[oA1 + (4*m4+j)*36 + 8*k8 + 4]);
                a00 = fma4(f0[j], b0v, a00); a01 = fma4(f0[j], b1v, a01);
                a10 = fma4(f1[j], b0v, a10); a11 = fma4(f1[j], b1v, a11);
            }
        }
        stf4(&PR[p0*36 + 8*k8], a00);      stf4(&PR[p0*36 + 8*k8 + 4], a01);
        stf4(&PR[(p0+32)*36 + 8*k8], a10); stf4(&PR[(p0+32)*36 + 8*k8 + 4], a11);
    }
    __syncthreads();

    // ---- PH12 + epilogue fused: fusion = lrelu(sv+tv^T) + M1@S0^T (regs),
    //      8-lane-group row softmax, direct global write. 256 thr. ----
    if (tid < 256) {
        int p0 = tid >> 3, q8 = tid & 7;
        float sp0 = sv[p0], sp1 = sv[p0+32];
        float4 tq0 = ldf4(&tv[8*q8]), tq1 = ldf4(&tv[8*q8 + 4]);
        float4 a00 = lrelu4(sp0, tq0), a01 = lrelu4(sp0, tq1);
        float4 a10 = lrelu4(sp1, tq0), a11 = lrelu4(sp1, tq1);
        #pragma unroll
        for (int m4 = 0; m4 < 8; ++m4) {
            float4 av0 = ldf4(&PR[p0*36 + 4*m4]);
            float4 av1 = ldf4(&PR[(p0+32)*36 + 4*m4]);
            const float* f0 = (const float*)&av0;
            const float* f1 = (const float*)&av1;
            #pragma unroll
            for (int j = 0; j < 4; ++j) {
                float4 s0v = ldf4(&xr[oS0T + (4*m4+j)*68 + 8*q8]);
                float4 s1vv = ldf4(&xr[oS0T + (4*m4+j)*68 + 8*q8 + 4]);
                a00 = fma4(f0[j], s0v, a00); a01 = fma4(f0[j], s1vv, a01);
                a10 = fma4(f1[j], s0v, a10); a11 = fma4(f1[j], s1vv, a11);
            }
        }
        size_t base = (size_t)g * 4096;
        {   // row p0
            float mx = fmaxf(vmax4(a00), vmax4(a01));
            mx = fmaxf(mx, __shfl_xor(mx,1)); mx = fmaxf(mx, __shfl_xor(mx,2)); mx = fmaxf(mx, __shfl_xor(mx,4));
            float4 e0 = exp4(a00, mx), e1 = exp4(a01, mx);
            float sm = vsum4(e0) + vsum4(e1);
            sm += __shfl_xor(sm,1); sm += __shfl_xor(sm,2); sm += __shfl_xor(sm,4);
            float inv = 1.f/sm;
            e0.x*=inv; e0.y*=inv; e0.z*=inv; e0.w*=inv;
            e1.x*=inv; e1.y*=inv; e1.z*=inv; e1.w*=inv;
            stf4(&out[base + (size_t)p0*64 + 8*q8], e0);
            stf4(&out[base + (size_t)p0*64 + 8*q8 + 4], e1);
        }
        {   // row p0+32
            float mx = fmaxf(vmax4(a10), vmax4(a11));
            mx = fmaxf(mx, __shfl_xor(mx,1)); mx = fmaxf(mx, __shfl_xor(mx,2)); mx = fmaxf(mx, __shfl_xor(mx,4));
            float4 e0 = exp4(a10, mx), e1 = exp4(a11, mx);
            float sm = vsum4(e0) + vsum4(e1);
            sm += __shfl_xor(sm,1); sm += __shfl_xor(sm,2); sm += __shfl_xor(sm,4);
            float inv = 1.f/sm;
            e0.x*=inv; e0.y*=inv; e0.z*=inv; e0.w*=inv;
            e1.x*=inv; e1.y*=inv; e1.z*=inv; e1.w*=inv;
            stf4(&out[base + (size_t)(p0+32)*64 + 8*q8], e0);
            stf4(&out[base + (size_t)(p0+32)*64 + 8*q8 + 4], e1);
        }
    }
}

// ================== SPATIAL: 16384 graphs of 25 nodes, 256 threads ==================
__global__ __launch_bounds__(256, 4)
void spatial_kernel(const float* __restrict__ src, const float* __restrict__ wvg,
                    const float* __restrict__ WpT0, const float* __restrict__ WpT1,
                    const float* __restrict__ b0, const float* __restrict__ b1,
                    float* __restrict__ out, int nwg8)
{
    __shared__ __align__(16) float Rx0[1700];
    __shared__ __align__(16) float RA0[700];
    __shared__ __align__(16) float RPR[816];
    __shared__ __align__(16) float RS0[500];
    __shared__ __align__(16) float sv[32], tv[32], ua[32], va[32], rxa[8], rsa[8];

    float* x0  = Rx0;
    float* A1  = Rx0;          // [12][20] -> B (in place)
    float* A1T = Rx0 + 240;    // [12][20] -> BT (in place)
    float* P1T = Rx0 + 480;    // [5][12]
    float* S1  = Rx0 + 540;    // [12][12]
    float* T1  = Rx0 + 744;    // [12][5]
    float* A0  = RA0;
    float* P0T = RPR;
    float* x1  = RPR;
    float* M1  = RPR;
    float* S0  = RS0;

    const int t = threadIdx.x;
    const int g = (blockIdx.x & 7) * nwg8 + (blockIdx.x >> 3);
    const int b = g >> 6, inner = g & 63;
    const float* srcb = src + (size_t)b*102400 + inner*25;

    for (int i = t; i < 400; i += 256) {
        int r = i % 25, c0 = (i / 25) << 2;
        float4 v;
        v.x = srcb[(c0+0)*1600 + r];
        v.y = srcb[(c0+1)*1600 + r];
        v.z = srcb[(c0+2)*1600 + r];
        v.w = srcb[(c0+3)*1600 + r];
        stf4(&x0[r*68 + c0], v);
    }
    __syncthreads();

    if (t < 50) {
        int which = t / 25, p = t - which*25;
        const float* w = wvg + which*64;
        float a = 0.f;
        #pragma unroll
        for (int c4 = 0; c4 < 16; ++c4) a += dot4(ldf4(&x0[p*68 + 4*c4]), ldf4(&w[4*c4]));
        if (which) tv[p] = a; else sv[p] = a;
    }
    for (int i = t; i < 336; i += 256) {
        int k = i / 28, m = i - k*28;
        float a = 0.f;
        if (m < 25) {
            #pragma unroll
            for (int c4 = 0; c4 < 16; ++c4) a += dot4(ldf4(&WpT0[k*64 + 4*c4]), ldf4(&x0[m*68 + 4*c4]));
        }
        P0T[k*28 + m] = a;
    }
    __syncthreads();

    for (int i = t; i < 700; i += 256) {
        int p = i / 28, q = i - p*28;
        A0[i] = (q < 25) ? lrelu(sv[p] + tv[q]) : -1e30f;
    }
    __syncthreads();

    for (int i = t; i < 300; i += 256) {
        int p = i / 12, k = i - p*12;
        float acc = b0[k];
        #pragma unroll
        for (int m4 = 0; m4 < 7; ++m4) acc += dot4(ldf4(&A0[p*28 + 4*m4]), ldf4(&P0T[k*28 + 4*m4]));
        S0[p*20 + k] = acc;
    }
    __syncthreads();

    if (t < 25) {
        float4 r[3]; float mx = -1e30f;
        #pragma unroll
        for (int u = 0; u < 3; ++u) { r[u] = ldf4(&S0[t*20 + 4*u]); mx = fmaxf(mx, vmax4(r[u])); }
        float sm = 0.f;
        #pragma unroll
        for (int u = 0; u < 3; ++u) { r[u] = exp4(r[u], mx); sm += vsum4(r[u]); }
        float inv = 1.f/sm;
        #pragma unroll
        for (int u = 0; u < 3; ++u) {
            r[u].x *= inv; r[u].y *= inv; r[u].z *= inv; r[u].w *= inv;
            stf4(&S0[t*20 + 4*u], r[u]);
        }
    }
    __syncthreads();

    if (t < 96) {
        int k = t >> 3, c0 = (t & 7) << 3;
        float4 a = {0,0,0,0}, bb = {0,0,0,0};
        #pragma unroll
        for (int p = 0; p < 25; ++p) {
            float s = S0[p*20 + k];
            a  = fma4(s, ldf4(&x0[p*68 + c0]), a);
            bb = fma4(s, ldf4(&x0[p*68 + c0 + 4]), bb);
        }
        stf4(&x1[k*68 + c0], a);
        stf4(&x1[k*68 + c0 + 4], bb);
    }
    __syncthreads();

    if (t < 48) {
        int which = t / 12, p = t - which*12;
        const float* w = wvg + (2+which)*64;
        float a = 0.f;
        #pragma unroll
        for (int c4 = 0; c4 < 16; ++c4) a += dot4(ldf4(&x1[p*68 + 4*c4]), ldf4(&w[4*c4]));
        if (which == 0) sv[p] = a; else if (which == 1) tv[p] = a;
        else if (which == 2) ua[p] = a; else va[p] = a;
    }
    for (int i = t; i < 60; i += 256) {
        int j = i / 12, k = i - j*12;
        float a = 0.f;
        #pragma unroll
        for (int c4 = 0; c4 < 16; ++c4) a += dot4(ldf4(&WpT1[j*64 + 4*c4]), ldf4(&x1[k*68 + 4*c4]));
        P1T[j*12 + k] = a;
    }
    __syncthreads();

    // A1, A1T
    for (int i = t; i < 288; i += 256) {
        int mat = i / 144, rr = (i - mat*144) / 12, q = i % 12;
        if (mat == 0) A1 [rr*20 + q] = lrelu(sv[rr] + tv[q]);
        else          A1T[rr*20 + q] = lrelu(sv[q] + tv[rr]);
    }
    __syncthreads();

    // G1: S1raw = A1@P1 + b1
    for (int i = t; i < 60; i += 256) {
        int m = i / 5, j = i - m*5;
        float acc = b1[j];
        #pragma unroll
        for (int k4 = 0; k4 < 3; ++k4) acc += dot4(ldf4(&A1[m*20 + 4*k4]), ldf4(&P1T[j*12 + 4*k4]));
        S1[m*12 + j] = acc;
    }
    __syncthreads();

    // G2: softmax S1 rows
    if (t < 12) {
        float mx = -1e30f;
        float r0 = S1[t*12+0], r1 = S1[t*12+1], r2 = S1[t*12+2], r3 = S1[t*12+3], r4 = S1[t*12+4];
        mx = fmaxf(fmaxf(fmaxf(r0,r1), fmaxf(r2,r3)), r4);
        r0 = __expf(r0-mx); r1 = __expf(r1-mx); r2 = __expf(r2-mx); r3 = __expf(r3-mx); r4 = __expf(r4-mx);
        float inv = 1.f/(r0+r1+r2+r3+r4);
        S1[t*12+0] = r0*inv; S1[t*12+1] = r1*inv; S1[t*12+2] = r2*inv; S1[t*12+3] = r3*inv; S1[t*12+4] = r4*inv;
    }
    __syncthreads();

    // G2b: rxa/rsa = S1^T . (u,v)
    if (t < 10) {
        int which = t / 5, k = t - which*5;
        float a = 0.f;
        #pragma unroll
        for (int n = 0; n < 12; ++n) a += S1[n*12 + k] * (which ? va[n] : ua[n]);
        if (which) rsa[k] = a; else rxa[k] = a;
    }
    __syncthreads();

    // G3: T1 = S1 @ A2 (A2 = lrelu(rxa + rsa^T) on the fly)  [12][5]
    if (t < 60) {
        int m = t / 5, k = t - m*5;
        float rsk = rsa[k];
        float acc = 0.f;
        #pragma unroll
        for (int j = 0; j < 5; ++j) acc += S1[m*12 + j] * lrelu(rxa[j] + rsk);
        T1[m*5 + k] = acc;
    }
    __syncthreads();

    // G4: B = A1 + T1@S1^T (in place); BT into A1T
    if (t < 144) {
        int m = t / 12, n = t - m*12;
        float acc = A1[m*20 + n];
        #pragma unroll
        for (int j = 0; j < 5; ++j) acc += T1[m*5 + j] * S1[n*12 + j];
        A1[m*20 + n] = acc;
        A1T[n*20 + m] = acc;
    }
    __syncthreads();

    // G5: M1 = S0 @ B (row-dot with BT in A1T)
    for (int i = t; i < 300; i += 256) {
        int p = i / 12, k = i - p*12;
        float acc = 0.f;
        #pragma unroll
        for (int m4 = 0; m4 < 3; ++m4) acc += dot4(ldf4(&S0[p*20 + 4*m4]), ldf4(&A1T[k*20 + 4*m4]));
        M1[p*20 + k] = acc;
    }
    __syncthreads();

    // G6: fusion = A0 + M1@S0^T
    for (int i = t; i < 625; i += 256) {
        int p = i / 25, q = i - p*25;
        float acc = A0[p*28 + q];
        #pragma unroll
        for (int m4 = 0; m4 < 3; ++m4) acc += dot4(ldf4(&M1[p*20 + 4*m4]), ldf4(&S0[q*20 + 4*m4]));
        A0[p*28 + q] = acc;
    }
    __syncthreads();

    // stats
    if (t < 25) {
        float4 r[7]; float mx = -1e30f;
        #pragma unroll
        for (int u = 0; u < 7; ++u) { r[u] = ldf4(&A0[t*28 + 4*u]); mx = fmaxf(mx, vmax4(r[u])); }
        float sm = 0.f;
        #pragma unroll
        for (int u = 0; u < 7; ++u) sm += vsum4(exp4(r[u], mx));
        sv[t] = mx; tv[t] = 1.f/sm;
    }
    __syncthreads();

    for (int i = t; i < 625; i += 256) {
        int p = i / 25, q = i - p*25;
        out[(size_t)g*625 + i] = __expf(A0[p*28 + q] - sv[p]) * tv[p];
    }
}

extern "C" void kernel_launch(void* const* d_in, const int* in_sizes, int n_in,
                              void* d_out, int out_size, void* d_ws, size_t ws_size,
                              hipStream_t stream) {
    const float* src = (const float*)d_in[0];
    const float* W   = (const float*)d_in[1];
    float* ws = (float*)d_ws;

    prep_kernel<<<16, 64, 0, stream>>>(W,
        (const float*)d_in[2],  (const float*)d_in[3],
        (const float*)d_in[6],  (const float*)d_in[7],
        (const float*)d_in[10], (const float*)d_in[11],
        (const float*)d_in[4],  (const float*)d_in[5],
        (const float*)d_in[8],  (const float*)d_in[9],
        (const float*)d_in[12], (const float*)d_in[13],
        (const float*)d_in[14], (const float*)d_in[16],
        (const float*)d_in[18], (const float*)d_in[20],
        ws);

    float* out = (float*)d_out;
    spatial_kernel<<<16384, 256, 0, stream>>>(
        src, ws, ws + 768, ws + 1536,
        (const float*)d_in[15], (const float*)d_in[17],
        out, 16384/8);
    temporal_kernel<<<6400, 512, 0, stream>>>(
        src, ws + 384,
        (const float*)d_in[18], (const float*)d_in[19],
        (const float*)d_in[20], (const float*)d_in[21],
        out + 10240000, 6400/8);
}